// Round 2
// baseline (618.038 us; speedup 1.0000x reference)
//
#include <hip/hip_runtime.h>

// Fastfood transform: out = (1/n) * H (G .* P( H (B .* x) )) per row,
// n = 16384, 4096 rows, fp32. Both 1/sqrt(n) folded into one 1/n at the end.
//
// PERSISTENT-BLOCK version: grid = 512 blocks (2/CU), each block processes
// rows {bid, bid+512, ...} and software-prefetches the next row's x into
// registers (p[8]) while the current row's gather + FWHT#2 run, so the HBM
// read stream overlaps the LDS/VALU compute. Stores overlap naturally.
//
// One block (512 threads, 8 waves) per row-slot; 64 KiB LDS = the row.
//
// Element index bits: i = [A(3)|Bb(3)|C(3)|D(3)|cl(2)], f4 index j = i>>2.
// Thread id t = [tu(3)|tv(3)|tw(3)] (tu = wave). Entry: r[m] = f4 at
// j = m*512 + t  ->  (A=m slot, Bb=tu, C=tv, D=tw).
//
// FWHT_16384 = pass1 (cl+A, 5 bits in regs)
//            + round1: WAVE-LOCAL swap slots<->tw   (butterfly D)   no barrier
//            + round2: WAVE-LOCAL swap slots<->tv   (butterfly C)   no barrier
//            + round3: cross-wave rotation, slots<-Bb, A->tu-pos    1 barrier
// Exit: r[m] = f4 at j = tu*512 + m*64 + tv*8 + tw (natural/coalesced).
//
// Bank-group check (f4 units, group = addr&7; every 8 consecutive lanes
// (fixed tv, tw=0..7) must hit 8 distinct groups):
//  r1 W: tv*64+m*8+(tw^m)        grp=tw^m   OK
//  r1 R: tv*64+tw*8+(m^tw)       grp=m^tw   OK
//  r2 W: tv*64+m*8+tw            grp=tw     OK
//  r2 R: m*64+tv*8+tw            grp=tw     OK
//  r3 W: tu*512+tw*64+m*8+(tv^tw) grp=tv^tw OK   (own region)
//  r3 R: m*512+tu*64+tv*8+(tw^tu) grp=tw^tu OK   (tu uniform per wave)
//  natural W / store: tu*512+m*64+tv*8+tw   grp=tw OK

#define L_N 16384

__device__ __forceinline__ float4 f4add(float4 a, float4 b) {
    return make_float4(a.x + b.x, a.y + b.y, a.z + b.z, a.w + b.w);
}
__device__ __forceinline__ float4 f4sub(float4 a, float4 b) {
    return make_float4(a.x - b.x, a.y - b.y, a.z - b.z, a.w - b.w);
}

// FWHT_4 within one float4 (the cl bits)
__device__ __forceinline__ void fwht4_inner(float4& a) {
    float s0 = a.x + a.y, d0 = a.x - a.y;
    float s1 = a.z + a.w, d1 = a.z - a.w;
    a.x = s0 + s1; a.y = d0 + d1; a.z = s0 - s1; a.w = d0 - d1;
}

// FWHT_8 across the 8 float4 slots (vectorized over the 4 inner lanes)
__device__ __forceinline__ void fwht8_vec(float4 v[8]) {
    #pragma unroll
    for (int s = 1; s < 8; s <<= 1) {
        #pragma unroll
        for (int k = 0; k < 8; ++k) {
            if ((k & s) == 0) {
                float4 a = v[k], b = v[k + s];
                v[k]     = f4add(a, b);
                v[k + s] = f4sub(a, b);
            }
        }
    }
}

// Full FWHT_16384 (unnormalized). Entry: r[m] = f4 at j = m*512 + t.
// Exit: r[m] = f4 at j = tu*512 + m*64 + tv*8 + tw.
// Contains ONE internal __syncthreads (before the cross-wave read).
// No trailing sync; caller must sync before reusing lds4 (WAR vs r3 reads).
__device__ __forceinline__ void fwht16384(float4 (&r)[8], float4* lds4,
                                          int tu, int tv, int tw) {
    // pass1: cl (2 bits) + A (3 slot bits)
    #pragma unroll
    for (int k = 0; k < 8; ++k) fwht4_inner(r[k]);
    fwht8_vec(r);

    float4* w = lds4 + tu * 512;   // this wave's private 8 KiB region

    // round1 (wave-local): slots<->tw. After: r[m] = elem(A=tw, C=tv, D=m)
    #pragma unroll
    for (int m = 0; m < 8; ++m) w[tv * 64 + m * 8 + (tw ^ m)] = r[m];
    #pragma unroll
    for (int m = 0; m < 8; ++m) r[m] = w[tv * 64 + tw * 8 + (m ^ tw)];
    fwht8_vec(r);          // D

    // round2 (wave-local): slots<->tv. After: r[m] = elem(A=tw, C=m, D=tv)
    #pragma unroll
    for (int m = 0; m < 8; ++m) w[tv * 64 + m * 8 + tw] = r[m];
    #pragma unroll
    for (int m = 0; m < 8; ++m) r[m] = w[m * 64 + tv * 8 + tw];
    fwht8_vec(r);          // C

    // round3 (cross-wave rotation): write own region, read everywhere.
    // After: r[m] = elem(A=tu, Bb=m, C=tv, D=tw)  -> natural exit layout.
    #pragma unroll
    for (int m = 0; m < 8; ++m) w[tw * 64 + m * 8 + (tv ^ tw)] = r[m];
    __syncthreads();
    #pragma unroll
    for (int m = 0; m < 8; ++m) r[m] = lds4[m * 512 + tu * 64 + tv * 8 + (tw ^ tu)];
    fwht8_vec(r);          // Bb
}

extern "C" __global__ void __launch_bounds__(512, 4)
fastfood_kernel(const float* __restrict__ x,
                const float* __restrict__ Bv,
                const float* __restrict__ Gv,
                const int*   __restrict__ Pi,
                float* __restrict__ out,
                int rows)
{
    __shared__ float4 lds4[L_N / 4];          // 64 KiB, exactly one row
    float* lds = (float*)lds4;

    const int t  = threadIdx.x;
    const int tu = t >> 6, tv = (t >> 3) & 7, tw = t & 7;
    const int nb = (int)gridDim.x;

    const float4* b4 = (const float4*)Bv;
    const float4* g4 = (const float4*)Gv;
    const int4*   p4 = (const int4*)Pi;

    int row = (int)blockIdx.x;
    if (row >= rows) return;

    float4 r[8], p[8];

    // initial row load (coalesced: per slot, lanes consecutive), fold in B
    {
        const float4* x4 = (const float4*)(x + (long)row * L_N);
        #pragma unroll
        for (int m = 0; m < 8; ++m) {
            float4 a = x4[m * 512 + t];
            float4 b = b4[m * 512 + t];
            r[m] = make_float4(a.x * b.x, a.y * b.y, a.z * b.z, a.w * b.w);
        }
    }

    while (true) {
        // ================= FWHT #1 =================
        fwht16384(r, lds4, tu, tv, tw);
        __syncthreads();   // all round3 reads done before natural write (WAR)

        // natural layout write for the permutation gather (own region, grp=tw)
        #pragma unroll
        for (int m = 0; m < 8; ++m) lds4[tu * 512 + m * 64 + tv * 8 + tw] = r[m];

        // prefetch next row's x: in flight under gather + FWHT#2 (~5-6 us)
        const int  nrow = row + nb;
        const bool more = nrow < rows;          // uniform across block
        if (more) {
            const float4* xn = (const float4*)(x + (long)nrow * L_N);
            #pragma unroll
            for (int m = 0; m < 8; ++m) p[m] = xn[m * 512 + t];
        }
        __syncthreads();

        // permutation + G: thread owns f4 index j = k*512 + t (coalesced
        // Pi/G, L2-resident); result matches FWHT#2 entry layout (slots = A).
        #pragma unroll
        for (int k = 0; k < 8; ++k) {
            int4   pp = p4[k * 512 + t];
            float4 g  = g4[k * 512 + t];
            r[k] = make_float4(lds[pp.x] * g.x, lds[pp.y] * g.y,
                               lds[pp.z] * g.z, lds[pp.w] * g.w);
        }
        __syncthreads();   // all gather reads done before FWHT#2 writes LDS

        // ================= FWHT #2 =================
        fwht16384(r, lds4, tu, tv, tw);

        // store, both normalizations folded; coalesced per slot.
        // Stores are fire-and-forget: they overlap the next row's compute.
        const float sc = 1.0f / (float)L_N;
        float4* o4 = (float4*)(out + (long)row * L_N);
        #pragma unroll
        for (int m = 0; m < 8; ++m) {
            float4 a = r[m];
            o4[tu * 512 + m * 64 + tv * 8 + tw] =
                make_float4(a.x * sc, a.y * sc, a.z * sc, a.w * sc);
        }

        if (!more) break;
        __syncthreads();   // FWHT#2 round3 reads done before next round1 write

        // consume prefetch, fold in B (B/G/Pi are L1/L2-resident re-reads)
        #pragma unroll
        for (int m = 0; m < 8; ++m) {
            float4 b = b4[m * 512 + t];
            r[m] = make_float4(p[m].x * b.x, p[m].y * b.y,
                               p[m].z * b.z, p[m].w * b.w);
        }
        row = nrow;
    }
}

extern "C" void kernel_launch(void* const* d_in, const int* in_sizes, int n_in,
                              void* d_out, int out_size, void* d_ws, size_t ws_size,
                              hipStream_t stream) {
    const float* x  = (const float*)d_in[0];
    const float* B  = (const float*)d_in[1];
    const float* G  = (const float*)d_in[2];
    const int*   Pi = (const int*)d_in[3];
    float* out = (float*)d_out;

    const int rows = in_sizes[0] / L_N;       // 4096
    int nb = rows < 512 ? rows : 512;         // 2 blocks/CU, persistent
    fastfood_kernel<<<nb, 512, 0, stream>>>(x, B, G, Pi, out, rows);
}

// Round 3
// 557.652 us; speedup vs baseline: 1.1083x; 1.1083x over previous
//
#include <hip/hip_runtime.h>

// Fastfood transform: out = (1/n) * H (G .* P( H (B .* x) )) per row,
// n = 16384, 4096 rows, fp32. Both 1/sqrt(n) folded into one 1/n at the end.
//
// v3: 256 threads x 16 float4/thread (6 index bits in regs -> only TWO LDS
// transpose rounds per FWHT instead of three: 38% less LDS traffic), raw
// s_barrier (no vmcnt drain -> register prefetch of the next row really
// floats under gather+FWHT#2), persistent 512 blocks (2/CU), nontemporal
// x/out so B/G/Pi stay L2-resident. __launch_bounds__(256,2) -> VGPR cap
// 256, live set ~160, no scratch spill (round-2 lesson: spill was the
// regression, WRITE_SIZE excess was the evidence).
//
// Index algebra: element i = [alpha(4)|beta(4)|gamma(4)|cl(2)], f4 index
// j = alpha*256 + beta*16 + gamma. Thread t = [th(4)|tl(4)] (wave = th>>2).
// Entry:  r[k] = row4[k*256 + t]            -> (alpha=k, beta=th, gamma=tl)
// pass1:  fwht4_inner (cl) + fwht16_vec (alpha)
// round1: WAVE-LOCAL slot<->tl swap (16-thread groups share th-region;
//         same-wave DS ops are in-order, no barrier):
//         W lds[th*256 + k*16 + (tl^k)], R lds[th*256 + tl*16 + (k^tl)]
//         -> (alpha=tl, beta=th, gamma=k); fwht16_vec (gamma)
// round2: cross-wave via swizzled canonical addr alpha*256+beta*16+(gamma^alpha):
//         BAR; W lds[tl*256 + th*16 + (k^tl)]; BAR;
//         R lds[th*256 + k*16 + (tl^th)] -> (alpha=th, beta=k, gamma=tl);
//         fwht16_vec (beta)
// Exit:   r[k] = elem j = th*256 + k*16 + tl  (natural, coalesced 256B chunks)
//
// Bank-groups (f4 addr & 7, must differ across 8 consecutive lanes = tl 0..7):
//  r1W (tl^k)&7 OK | r1R (k^tl)&7 OK | r2W (k^tl)&7 OK | r2R (tl^th)&7 OK
//  natural W: tl&7 OK | global load j=k*256+t fully coalesced
//
// Barriers are raw s_barrier preceded by s_waitcnt lgkmcnt(0) only: LDS
// ordering without draining vmcnt, so the 16 nontemporal prefetch loads
// issued before the gather stay in flight until consumed at loop top.
// All barriers are block-uniform (persistent loop condition is uniform).

#define L_N 16384

typedef float f4v __attribute__((ext_vector_type(4)));
typedef int   i4v __attribute__((ext_vector_type(4)));

__device__ __forceinline__ void lds_barrier() {
    asm volatile("s_waitcnt lgkmcnt(0)" ::: "memory");
    __builtin_amdgcn_s_barrier();
}

// FWHT_4 within one float4 (the cl bits)
__device__ __forceinline__ void fwht4_inner(f4v& a) {
    float s0 = a.x + a.y, d0 = a.x - a.y;
    float s1 = a.z + a.w, d1 = a.z - a.w;
    f4v n; n.x = s0 + s1; n.y = d0 + d1; n.z = s0 - s1; n.w = d0 - d1;
    a = n;
}

// FWHT_16 across the 16 float4 slots (vectorized over the 4 inner lanes)
__device__ __forceinline__ void fwht16_vec(f4v v[16]) {
    #pragma unroll
    for (int s = 1; s < 16; s <<= 1) {
        #pragma unroll
        for (int k = 0; k < 16; ++k) {
            if ((k & s) == 0) {
                f4v a = v[k], b = v[k + s];
                v[k]     = a + b;
                v[k + s] = a - b;
            }
        }
    }
}

// Full FWHT_16384 (unnormalized). Entry: r[k] = f4 at j = k*256 + t.
// Exit:  r[k] = f4 at j = th*256 + k*16 + tl (natural).
// Contains TWO raw barriers. No trailing barrier: the exit state only did
// own-region reads, so the caller's own-region natural write is in-order.
__device__ __forceinline__ void fwht16384(f4v (&r)[16], f4v* lds4,
                                          int th, int tl) {
    #pragma unroll
    for (int k = 0; k < 16; ++k) fwht4_inner(r[k]);   // cl
    fwht16_vec(r);                                    // alpha

    // round1 (wave-local): slot<->tl. 16-thread th-groups, own 4 KiB region.
    #pragma unroll
    for (int k = 0; k < 16; ++k) lds4[th * 256 + k * 16 + (tl ^ k)] = r[k];
    #pragma unroll
    for (int k = 0; k < 16; ++k) r[k] = lds4[th * 256 + tl * 16 + (k ^ tl)];
    fwht16_vec(r);                                    // gamma

    lds_barrier();   // r1 reads (all groups) done before cross-region writes

    // round2 (cross-wave): write swizzled canonical, read own alpha-region
    #pragma unroll
    for (int k = 0; k < 16; ++k) lds4[tl * 256 + th * 16 + (k ^ tl)] = r[k];
    lds_barrier();   // cross writes visible
    #pragma unroll
    for (int k = 0; k < 16; ++k) r[k] = lds4[th * 256 + k * 16 + (tl ^ th)];
    fwht16_vec(r);                                    // beta
}

extern "C" __global__ void __launch_bounds__(256, 2)
fastfood_kernel(const float* __restrict__ x,
                const float* __restrict__ Bv,
                const float* __restrict__ Gv,
                const int*   __restrict__ Pi,
                float* __restrict__ out,
                int rows)
{
    __shared__ f4v lds4[L_N / 4];             // 64 KiB, exactly one row
    float* lds = (float*)lds4;

    const int t  = threadIdx.x;
    const int th = t >> 4, tl = t & 15;
    const int nb = (int)gridDim.x;

    const f4v* b4 = (const f4v*)Bv;
    const f4v* g4 = (const f4v*)Gv;
    const i4v* p4 = (const i4v*)Pi;

    int row = (int)blockIdx.x;
    if (row >= rows) return;

    f4v r[16], p[16];

    // initial row load (fully coalesced, nontemporal: read-once stream)
    {
        const f4v* x4 = (const f4v*)(x + (long)row * L_N);
        #pragma unroll
        for (int k = 0; k < 16; ++k)
            p[k] = __builtin_nontemporal_load(&x4[k * 256 + t]);
        #pragma unroll
        for (int k = 0; k < 16; ++k) r[k] = p[k] * b4[k * 256 + t];
    }

    while (true) {
        // ================= FWHT #1 =================
        fwht16384(r, lds4, th, tl);

        // natural write for the gather (own th-region, in-order, no barrier)
        #pragma unroll
        for (int k = 0; k < 16; ++k) lds4[th * 256 + k * 16 + tl] = r[k];

        // prefetch next row: floats under gather + FWHT#2 (raw barriers
        // don't drain vmcnt; consumed at loop top)
        const int  nrow = row + nb;
        const bool more = nrow < rows;           // uniform across block
        if (more) {
            const f4v* xn = (const f4v*)(x + (long)nrow * L_N);
            #pragma unroll
            for (int k = 0; k < 16; ++k)
                p[k] = __builtin_nontemporal_load(&xn[k * 256 + t]);
        }

        lds_barrier();   // natural writes visible to all for the gather

        // permutation + G: thread owns f4 j = k*256 + t (coalesced Pi/G,
        // L2-resident); result matches FWHT#2 entry layout.
        #pragma unroll
        for (int k = 0; k < 16; ++k) {
            i4v pp = p4[k * 256 + t];
            f4v g  = g4[k * 256 + t];
            f4v v;
            v.x = lds[pp.x] * g.x; v.y = lds[pp.y] * g.y;
            v.z = lds[pp.z] * g.z; v.w = lds[pp.w] * g.w;
            r[k] = v;
        }

        lds_barrier();   // all gather reads done before FWHT#2 writes LDS

        // ================= FWHT #2 =================
        fwht16384(r, lds4, th, tl);

        // store, both normalizations folded; nontemporal (write-once stream)
        const float sc = 1.0f / (float)L_N;
        f4v* o4 = (f4v*)(out + (long)row * L_N);
        #pragma unroll
        for (int k = 0; k < 16; ++k)
            __builtin_nontemporal_store(r[k] * sc, &o4[th * 256 + k * 16 + tl]);

        if (!more) break;

        // consume prefetch, fold in B. Loop-wrap LDS hazard: this iter's
        // last LDS reads were own-region (r2 R); next r1 write is own-region
        // too -> same-wave in-order, no barrier needed.
        #pragma unroll
        for (int k = 0; k < 16; ++k) r[k] = p[k] * b4[k * 256 + t];
        row = nrow;
    }
}

extern "C" void kernel_launch(void* const* d_in, const int* in_sizes, int n_in,
                              void* d_out, int out_size, void* d_ws, size_t ws_size,
                              hipStream_t stream) {
    const float* x  = (const float*)d_in[0];
    const float* B  = (const float*)d_in[1];
    const float* G  = (const float*)d_in[2];
    const int*   Pi = (const int*)d_in[3];
    float* out = (float*)d_out;

    const int rows = in_sizes[0] / L_N;       // 4096
    int nb = rows < 512 ? rows : 512;         // 2 blocks/CU, persistent
    fastfood_kernel<<<nb, 256, 0, stream>>>(x, B, G, Pi, out, rows);
}

// Round 4
// 473.010 us; speedup vs baseline: 1.3066x; 1.1789x over previous
//
#include <hip/hip_runtime.h>

// Fastfood transform: out = (1/n) * H (G .* P( H (B .* x) )) per row,
// n = 16384, 4096 rows, fp32. Both 1/sqrt(n) folded into one 1/n at the end.
//
// v4 = v1 shape (the best measured: ~123-133 us kernel) + two latency fixes.
//   - 4096 INDEPENDENT blocks (1 row each), 512 threads (8 waves), 64 KiB LDS
//     -> 2 blocks/CU, 16 waves/CU. Cross-block phase offset + HW dispatch
//     pipelining gives the memory/compute overlap the persistent version
//     (v3: 8 waves/CU, 237 us) lost. Occupancy was the lever, not LDS traffic.
//   - Raw s_barrier with lgkmcnt-only wait (no vmcnt drain): global loads can
//     stay in flight across barriers.
//   - Pi/G gather loads issued BEFORE the gather barrier (after the natural
//     write), so their ~200cy L2 latency hides under the barrier wait.
//     pi[8]+g[8] = 64 VGPRs live only while r[] is dead -> peak ~110 < 128.
//
// Element index bits: i = [A(3)|Bb(3)|C(3)|D(3)|cl(2)], f4 index j = i>>2.
// Thread id t = [tu(3)|tv(3)|tw(3)] (tu = wave). Entry: r[m] = f4 at
// j = m*512 + t  ->  (A=m slot, Bb=tu, C=tv, D=tw).
//
// FWHT_16384 = pass1 (cl+A, 5 bits in regs)
//            + round1: WAVE-LOCAL swap slots<->tw   (butterfly D)   no barrier
//            + round2: WAVE-LOCAL swap slots<->tv   (butterfly C)   no barrier
//            + round3: cross-wave rotation, slots<-Bb, A->tu-pos    1 barrier
// Exit: r[m] = f4 at j = tu*512 + m*64 + tv*8 + tw (natural/coalesced).
//
// Bank-group check (f4 units, group = addr&7; every 8 consecutive lanes
// (fixed tv, tw=0..7) must hit 8 distinct groups):
//  r1 W: tv*64+m*8+(tw^m)        grp=tw^m   OK
//  r1 R: tv*64+tw*8+(m^tw)       grp=m^tw   OK
//  r2 W: tv*64+m*8+tw            grp=tw     OK
//  r2 R: m*64+tv*8+tw            grp=tw     OK
//  r3 W: tu*512+tw*64+m*8+(tv^tw) grp=tv^tw OK   (own region)
//  r3 R: m*512+tu*64+tv*8+(tw^tu) grp=tw^tu OK   (tu uniform per wave)
//  natural W / store: tu*512+m*64+tv*8+tw   grp=tw OK

#define L_N 16384

__device__ __forceinline__ float4 f4add(float4 a, float4 b) {
    return make_float4(a.x + b.x, a.y + b.y, a.z + b.z, a.w + b.w);
}
__device__ __forceinline__ float4 f4sub(float4 a, float4 b) {
    return make_float4(a.x - b.x, a.y - b.y, a.z - b.z, a.w - b.w);
}

// Raw barrier: order LDS only; do NOT drain vmcnt (global loads stay in
// flight; the compiler inserts vmcnt waits at first use of the results).
__device__ __forceinline__ void lds_barrier() {
    asm volatile("s_waitcnt lgkmcnt(0)" ::: "memory");
    __builtin_amdgcn_s_barrier();
}

// FWHT_4 within one float4 (the cl bits)
__device__ __forceinline__ void fwht4_inner(float4& a) {
    float s0 = a.x + a.y, d0 = a.x - a.y;
    float s1 = a.z + a.w, d1 = a.z - a.w;
    a.x = s0 + s1; a.y = d0 + d1; a.z = s0 - s1; a.w = d0 - d1;
}

// FWHT_8 across the 8 float4 slots (vectorized over the 4 inner lanes)
__device__ __forceinline__ void fwht8_vec(float4 v[8]) {
    #pragma unroll
    for (int s = 1; s < 8; s <<= 1) {
        #pragma unroll
        for (int k = 0; k < 8; ++k) {
            if ((k & s) == 0) {
                float4 a = v[k], b = v[k + s];
                v[k]     = f4add(a, b);
                v[k + s] = f4sub(a, b);
            }
        }
    }
}

// Full FWHT_16384 (unnormalized). Entry: r[m] = f4 at j = m*512 + t.
// Exit: r[m] = f4 at j = tu*512 + m*64 + tv*8 + tw.
// Contains ONE internal barrier (before the cross-wave read).
// No trailing barrier; caller must barrier before reusing lds4 (WAR vs r3).
__device__ __forceinline__ void fwht16384(float4 (&r)[8], float4* lds4,
                                          int tu, int tv, int tw) {
    // pass1: cl (2 bits) + A (3 slot bits)
    #pragma unroll
    for (int k = 0; k < 8; ++k) fwht4_inner(r[k]);
    fwht8_vec(r);

    float4* w = lds4 + tu * 512;   // this wave's private 8 KiB region

    // round1 (wave-local): slots<->tw. After: r[m] = elem(A=tw, C=tv, D=m)
    #pragma unroll
    for (int m = 0; m < 8; ++m) w[tv * 64 + m * 8 + (tw ^ m)] = r[m];
    #pragma unroll
    for (int m = 0; m < 8; ++m) r[m] = w[tv * 64 + tw * 8 + (m ^ tw)];
    fwht8_vec(r);          // D

    // round2 (wave-local): slots<->tv. After: r[m] = elem(A=tw, C=m, D=tv)
    #pragma unroll
    for (int m = 0; m < 8; ++m) w[tv * 64 + m * 8 + tw] = r[m];
    #pragma unroll
    for (int m = 0; m < 8; ++m) r[m] = w[m * 64 + tv * 8 + tw];
    fwht8_vec(r);          // C

    // round3 (cross-wave rotation): write own region, read everywhere.
    // After: r[m] = elem(A=tu, Bb=m, C=tv, D=tw)  -> natural exit layout.
    #pragma unroll
    for (int m = 0; m < 8; ++m) w[tw * 64 + m * 8 + (tv ^ tw)] = r[m];
    lds_barrier();
    #pragma unroll
    for (int m = 0; m < 8; ++m) r[m] = lds4[m * 512 + tu * 64 + tv * 8 + (tw ^ tu)];
    fwht8_vec(r);          // Bb
}

extern "C" __global__ void __launch_bounds__(512, 4)
fastfood_kernel(const float* __restrict__ x,
                const float* __restrict__ Bv,
                const float* __restrict__ Gv,
                const int*   __restrict__ Pi,
                float* __restrict__ out)
{
    __shared__ float4 lds4[L_N / 4];          // 64 KiB, exactly one row
    float* lds = (float*)lds4;

    const int t  = threadIdx.x;
    const int tu = t >> 6, tv = (t >> 3) & 7, tw = t & 7;
    const long row = blockIdx.x;

    const float4* x4 = (const float4*)(x + row * (long)L_N);
    const float4* b4 = (const float4*)Bv;
    float4 r[8];

    // load row (coalesced: per slot, lanes consecutive), fold in B
    #pragma unroll
    for (int m = 0; m < 8; ++m) {
        float4 a = x4[m * 512 + t];
        float4 b = b4[m * 512 + t];
        r[m] = make_float4(a.x * b.x, a.y * b.y, a.z * b.z, a.w * b.w);
    }

    // ================= FWHT #1 =================
    fwht16384(r, lds4, tu, tv, tw);
    lds_barrier();     // all round3 cross-reads done before natural write (WAR)

    // natural layout write for the permutation gather (own region, grp=tw)
    #pragma unroll
    for (int m = 0; m < 8; ++m) lds4[tu * 512 + m * 64 + tv * 8 + tw] = r[m];

    // issue Pi/G loads NOW: their L2 latency hides under the barrier wait
    // (raw barrier does not drain vmcnt; waits appear at first use below).
    int4   pi[8];
    float4 gg[8];
    {
        const int4*   p4 = (const int4*)Pi;
        const float4* g4 = (const float4*)Gv;
        #pragma unroll
        for (int k = 0; k < 8; ++k) pi[k] = p4[k * 512 + t];
        #pragma unroll
        for (int k = 0; k < 8; ++k) gg[k] = g4[k * 512 + t];
    }

    lds_barrier();     // natural writes visible to all waves

    // permutation + G: thread owns f4 index j = k*512 + t
    #pragma unroll
    for (int k = 0; k < 8; ++k) {
        int4   p = pi[k];
        float4 g = gg[k];
        r[k] = make_float4(lds[p.x] * g.x, lds[p.y] * g.y,
                           lds[p.z] * g.z, lds[p.w] * g.w);
    }
    lds_barrier();     // all gather reads done before FWHT#2 writes LDS

    // ================= FWHT #2 ================= (same entry layout: slots=A)
    fwht16384(r, lds4, tu, tv, tw);

    // store, both normalizations folded; coalesced per slot
    const float sc = 1.0f / (float)L_N;
    float4* o4 = (float4*)(out + row * (long)L_N);
    #pragma unroll
    for (int m = 0; m < 8; ++m) {
        float4 a = r[m];
        o4[tu * 512 + m * 64 + tv * 8 + tw] =
            make_float4(a.x * sc, a.y * sc, a.z * sc, a.w * sc);
    }
}

extern "C" void kernel_launch(void* const* d_in, const int* in_sizes, int n_in,
                              void* d_out, int out_size, void* d_ws, size_t ws_size,
                              hipStream_t stream) {
    const float* x  = (const float*)d_in[0];
    const float* B  = (const float*)d_in[1];
    const float* G  = (const float*)d_in[2];
    const int*   Pi = (const int*)d_in[3];
    float* out = (float*)d_out;

    const int rows = in_sizes[0] / L_N;       // 4096
    fastfood_kernel<<<rows, 512, 0, stream>>>(x, B, G, Pi, out);
}